// Round 7
// baseline (138.185 us; speedup 1.0000x reference)
//
#include <hip/hip_runtime.h>

// out[m] = perspective(tKF[kf_ids[m]] @ [tMP[mp_ids[m]], 1])
// idxKF/idxMP are sorted aranges -> searchsorted == identity.
//
// R7: LDS bank-conflict fix. R6 stored the KF table AoS at 32 B stride ->
// random-kf ds_read_b128 piled 64 lanes onto 4 bank-groups (~16-way).
// Now SoA: 8 dword rows of [2048] (rows 0-3 = half2-packed KF rows 0,1;
// rows 4-7 = fp32 row 2). Per-edge reads are 8x ds_read_b32 with bank =
// (kf+c)%32, random kf -> ~2-way = free (m136). Same 64 KB -> 2 blocks/CU
// = 32 waves (max: 2048 thr/CU). Fused single pack kernel. nt id loads,
// normal stores, rcp divide. VGPR capped via __launch_bounds__(1024,8).

#define FX_ 320.0f
#define FY_ 320.0f
#define CX_ 320.0f
#define CY_ 240.0f

#define MAX_KF 2048
#define KF_STRIDE 2048
#define MAIN_BLOCK 1024
#define EPT 8

typedef int vint4 __attribute__((ext_vector_type(4)));

__device__ __forceinline__ unsigned pack_h2(float a, float b) {
    _Float16 ha = (_Float16)a, hb = (_Float16)b;
    unsigned short ua = __builtin_bit_cast(unsigned short, ha);
    unsigned short ub = __builtin_bit_cast(unsigned short, hb);
    return (unsigned)ua | ((unsigned)ub << 16);
}

__device__ __forceinline__ float2 unpack_h2(unsigned u) {
    _Float16 ha = __builtin_bit_cast(_Float16, (unsigned short)(u & 0xffffu));
    _Float16 hb = __builtin_bit_cast(_Float16, (unsigned short)(u >> 16));
    return make_float2((float)ha, (float)hb);
}

// --- fused prep:
//   tMP [N,3] -> tMPh [N] float4 (x,y,z,1)
//   tKF [K,16] -> SoA table: unsigned uRows[4][KF_STRIDE] ++ float fRows[4][KF_STRIDE]
__global__ __launch_bounds__(256) void pack_kernel(
    const float* __restrict__ tMP, const float* __restrict__ tKF,
    float4* __restrict__ tMPh, unsigned* __restrict__ kfU, float* __restrict__ kfF,
    int N_MP, int N_KF)
{
    int i = blockIdx.x * blockDim.x + threadIdx.x;
    if (i < N_MP) {
        const float* p = tMP + (size_t)i * 3;
        tMPh[i] = make_float4(p[0], p[1], p[2], 1.0f);
    }
    if (i < N_KF) {
        const float* K = tKF + (size_t)i * 16;
        float4 r0 = *reinterpret_cast<const float4*>(K + 0);
        float4 r1 = *reinterpret_cast<const float4*>(K + 4);
        float4 r2 = *reinterpret_cast<const float4*>(K + 8);
        kfU[0 * KF_STRIDE + i] = pack_h2(r0.x, r0.y);
        kfU[1 * KF_STRIDE + i] = pack_h2(r0.z, r0.w);
        kfU[2 * KF_STRIDE + i] = pack_h2(r1.x, r1.y);
        kfU[3 * KF_STRIDE + i] = pack_h2(r1.z, r1.w);
        kfF[0 * KF_STRIDE + i] = r2.x;
        kfF[1 * KF_STRIDE + i] = r2.y;
        kfF[2 * KF_STRIDE + i] = r2.z;
        kfF[3 * KF_STRIDE + i] = r2.w;
    }
}

__device__ __forceinline__ void project1(
    const unsigned* __restrict__ sH, const float* __restrict__ sF,
    int kf, const float4& pv, float* rx, float* ry)
{
    // 8x ds_read_b32, bank = (kf + c) % 32 -> conflict-free for random kf
    unsigned u0 = sH[0 * KF_STRIDE + kf];
    unsigned u1 = sH[1 * KF_STRIDE + kf];
    unsigned u2 = sH[2 * KF_STRIDE + kf];
    unsigned u3 = sH[3 * KF_STRIDE + kf];
    float a0 = sF[0 * KF_STRIDE + kf];
    float a1 = sF[1 * KF_STRIDE + kf];
    float a2 = sF[2 * KF_STRIDE + kf];
    float a3 = sF[3 * KF_STRIDE + kf];
    float2 h0 = unpack_h2(u0), h1 = unpack_h2(u1);
    float2 h2 = unpack_h2(u2), h3 = unpack_h2(u3);
    float P0 = fmaf(h0.x, pv.x, fmaf(h0.y, pv.y, fmaf(h1.x, pv.z, h1.y)));
    float P1 = fmaf(h2.x, pv.x, fmaf(h2.y, pv.y, fmaf(h3.x, pv.z, h3.y)));
    float P2 = fmaf(a0, pv.x, fmaf(a1, pv.y, fmaf(a2, pv.z, a3)));
    float inv = __builtin_amdgcn_rcpf(P2);
    *rx = fmaf(P0 * inv, FX_, CX_);
    *ry = fmaf(P1 * inv, FY_, CY_);
}

__global__ __launch_bounds__(MAIN_BLOCK, 8) void ba_project_soa_kernel(
    const float4*   __restrict__ tMPh,  // [N_MP] (x,y,z,1)
    const unsigned* __restrict__ kfU,   // [4][KF_STRIDE]
    const float*    __restrict__ kfF,   // [4][KF_STRIDE]
    const int*      __restrict__ kf_ids,
    const int*      __restrict__ mp_ids,
    float* __restrict__ out,            // [M,2]
    int M)
{
    // blocks with no edges exit before paying the 64 KB staging
    if ((size_t)blockIdx.x * MAIN_BLOCK * EPT >= (size_t)M) return;

    __shared__ unsigned sH[4 * KF_STRIDE];  // 32 KB
    __shared__ float    sF[4 * KF_STRIDE];  // 32 KB  -> 64 KB total, 2 blocks/CU
    {
        const float4* srcU = reinterpret_cast<const float4*>(kfU);
        const float4* srcF = reinterpret_cast<const float4*>(kfF);
        float4* dstU = reinterpret_cast<float4*>(sH);
        float4* dstF = reinterpret_cast<float4*>(sF);
        const int nv = 4 * KF_STRIDE / 4;   // 2048 float4 per table
        #pragma unroll
        for (int i = threadIdx.x; i < nv; i += MAIN_BLOCK) {
            dstU[i] = srcU[i];
            dstF[i] = srcF[i];
        }
    }
    __syncthreads();

    size_t tid = (size_t)blockIdx.x * MAIN_BLOCK + threadIdx.x;
    size_t m0 = tid * EPT;

    if (m0 + EPT <= (size_t)M) {
        // streaming ids: non-temporal (read-once; keep L2 for tMPh)
        vint4 ka = __builtin_nontemporal_load(reinterpret_cast<const vint4*>(kf_ids + m0));
        vint4 kb = __builtin_nontemporal_load(reinterpret_cast<const vint4*>(kf_ids + m0 + 4));
        vint4 ma = __builtin_nontemporal_load(reinterpret_cast<const vint4*>(mp_ids + m0));
        vint4 mb = __builtin_nontemporal_load(reinterpret_cast<const vint4*>(mp_ids + m0 + 4));
        int kf[EPT] = {ka.x, ka.y, ka.z, ka.w, kb.x, kb.y, kb.z, kb.w};
        int mp[EPT] = {ma.x, ma.y, ma.z, ma.w, mb.x, mb.y, mb.z, mb.w};
        float4 p[EPT];
        #pragma unroll
        for (int i = 0; i < EPT; ++i) p[i] = tMPh[mp[i]];   // 8 gathers in flight
        float res[2 * EPT];
        #pragma unroll
        for (int i = 0; i < EPT; ++i)
            project1(sH, sF, kf[i], p[i], &res[2 * i], &res[2 * i + 1]);
        float4* o = reinterpret_cast<float4*>(out + m0 * 2);
        #pragma unroll
        for (int j = 0; j < EPT / 2; ++j)
            o[j] = make_float4(res[4 * j], res[4 * j + 1], res[4 * j + 2], res[4 * j + 3]);
    } else if (m0 < (size_t)M) {
        for (size_t m = m0; m < (size_t)M; ++m) {
            float4 pv = tMPh[mp_ids[m]];
            float rx, ry;
            project1(sH, sF, kf_ids[m], pv, &rx, &ry);
            out[m * 2 + 0] = rx;
            out[m * 2 + 1] = ry;
        }
    }
}

// --- fallback (no ws / oversized N_KF): known-correct direct kernel ---
__global__ __launch_bounds__(256) void ba_project_direct_kernel(
    const float* __restrict__ tMP, const float* __restrict__ tKF,
    const int* __restrict__ kf_ids, const int* __restrict__ mp_ids,
    float* __restrict__ out, int M)
{
    int t = blockIdx.x * blockDim.x + threadIdx.x;
    int m0 = t * 4;
    int mEnd = (m0 + 4 < M) ? (m0 + 4) : M;
    for (int m = m0; m < mEnd; ++m) {
        int kf = kf_ids[m];
        int mp = mp_ids[m];
        const float* K = tKF + (size_t)kf * 16;
        float4 r0 = *reinterpret_cast<const float4*>(K + 0);
        float4 r1 = *reinterpret_cast<const float4*>(K + 4);
        float4 r2 = *reinterpret_cast<const float4*>(K + 8);
        const float* p = tMP + (size_t)mp * 3;
        float x = p[0], y = p[1], z = p[2];
        float P0 = fmaf(r0.x, x, fmaf(r0.y, y, fmaf(r0.z, z, r0.w)));
        float P1 = fmaf(r1.x, x, fmaf(r1.y, y, fmaf(r1.z, z, r1.w)));
        float P2 = fmaf(r2.x, x, fmaf(r2.y, y, fmaf(r2.z, z, r2.w)));
        float inv = 1.0f / P2;
        out[2 * (size_t)m + 0] = fmaf(P0 * inv, FX_, CX_);
        out[2 * (size_t)m + 1] = fmaf(P1 * inv, FY_, CY_);
    }
}

extern "C" void kernel_launch(void* const* d_in, const int* in_sizes, int n_in,
                              void* d_out, int out_size, void* d_ws, size_t ws_size,
                              hipStream_t stream) {
    const float* tMP    = (const float*)d_in[0]; // [N_MP,3]
    const float* tKF    = (const float*)d_in[1]; // [N_KF,4,4]
    const int*   kf_ids = (const int*)d_in[2];   // [M]
    const int*   mp_ids = (const int*)d_in[3];   // [M]
    float* out = (float*)d_out;                  // [M,2]
    int M    = in_sizes[2];
    int N_MP = in_sizes[0] / 3;
    int N_KF = in_sizes[1] / 16;

    const size_t KFU_BYTES = 4 * KF_STRIDE * sizeof(unsigned); // 32 KB
    const size_t KFF_BYTES = 4 * KF_STRIDE * sizeof(float);    // 32 KB
    size_t need_ws = KFU_BYTES + KFF_BYTES + (size_t)N_MP * sizeof(float4);

    if (N_KF <= MAX_KF && ws_size >= need_ws) {
        unsigned* kfU  = (unsigned*)d_ws;
        float*    kfF  = (float*)((char*)d_ws + KFU_BYTES);
        float4*   tMPh = (float4*)((char*)d_ws + KFU_BYTES + KFF_BYTES);
        int np = (N_MP > N_KF ? N_MP : N_KF);
        pack_kernel<<<(np + 255) / 256, 256, 0, stream>>>(
            tMP, tKF, tMPh, kfU, kfF, N_MP, N_KF);
        int perBlock = MAIN_BLOCK * EPT;
        int nb = (M + perBlock - 1) / perBlock;
        nb = ((nb + 511) / 512) * 512;           // uniform 2 blocks/CU
        ba_project_soa_kernel<<<nb, MAIN_BLOCK, 0, stream>>>(
            tMPh, kfU, kfF, kf_ids, mp_ids, out, M);
    } else {
        int threads = (M + 3) / 4;
        int grid = (threads + 255) / 256;
        ba_project_direct_kernel<<<grid, 256, 0, stream>>>(
            tMP, tKF, kf_ids, mp_ids, out, M);
    }
}

// Round 8
// 136.493 us; speedup vs baseline: 1.0124x; 1.0124x over previous
//
#include <hip/hip_runtime.h>

// out[m] = perspective(tKF[kf_ids[m]] @ [tMP[mp_ids[m]], 1])
// idxKF/idxMP are sorted aranges -> searchsorted == identity.
//
// R8: NO LDS. Every LDS-table variant (R2-R7, 48B/32B AoS, SoA) plateaued at
// 43-53 us: random-index LDS reads always bank-conflict (birthday problem),
// staging costs 24-32 MB FETCH + barrier, and 64-96 KB LDS caps occupancy at
// 16 waves/CU. Instead: packed 32 B KFE {half8 r01, float4 r2} in GLOBAL
// (64 KB -> L1/L2-hot), tMPh float4 gather. 3 scattered 16 B requests/edge
// (R1 had 6). TLP hides latency: no LDS + lean VGPR -> up to 32 waves/CU.
// EPT=4 single pass, nt id loads, normal stores, rcp divide.

#define FX_ 320.0f
#define FY_ 320.0f
#define CX_ 320.0f
#define CY_ 240.0f

#define MAX_KF 2048
#define EPT 4

typedef int vint4 __attribute__((ext_vector_type(4)));

struct alignas(16) KFE {   // 32 B
    float4 r01h;  // rows 0,1 as 8x fp16 (bit-packed)
    float4 r2;    // row 2 fp32 (denominator)
};

__device__ __forceinline__ unsigned pack_h2(float a, float b) {
    _Float16 ha = (_Float16)a, hb = (_Float16)b;
    unsigned short ua = __builtin_bit_cast(unsigned short, ha);
    unsigned short ub = __builtin_bit_cast(unsigned short, hb);
    return (unsigned)ua | ((unsigned)ub << 16);
}

__device__ __forceinline__ float2 unpack_h2(unsigned u) {
    _Float16 ha = __builtin_bit_cast(_Float16, (unsigned short)(u & 0xffffu));
    _Float16 hb = __builtin_bit_cast(_Float16, (unsigned short)(u >> 16));
    return make_float2((float)ha, (float)hb);
}

// --- fused prep: tMP [N,3] -> float4 (x,y,z,1); tKF [K,16] -> KFE (32 B) ---
__global__ __launch_bounds__(256) void pack_kernel(
    const float* __restrict__ tMP, const float* __restrict__ tKF,
    float4* __restrict__ tMPh, KFE* __restrict__ kfe,
    int N_MP, int N_KF)
{
    int i = blockIdx.x * blockDim.x + threadIdx.x;
    if (i < N_MP) {
        const float* p = tMP + (size_t)i * 3;
        tMPh[i] = make_float4(p[0], p[1], p[2], 1.0f);
    }
    if (i < N_KF) {
        const float* K = tKF + (size_t)i * 16;
        float4 r0 = *reinterpret_cast<const float4*>(K + 0);
        float4 r1 = *reinterpret_cast<const float4*>(K + 4);
        float4 r2 = *reinterpret_cast<const float4*>(K + 8);
        KFE e;
        unsigned u0 = pack_h2(r0.x, r0.y), u1 = pack_h2(r0.z, r0.w);
        unsigned u2 = pack_h2(r1.x, r1.y), u3 = pack_h2(r1.z, r1.w);
        e.r01h = make_float4(__builtin_bit_cast(float, u0), __builtin_bit_cast(float, u1),
                             __builtin_bit_cast(float, u2), __builtin_bit_cast(float, u3));
        e.r2 = r2;
        kfe[i] = e;
    }
}

__device__ __forceinline__ void project1(
    const float4& r01h, const float4& r2, const float4& pv, float* rx, float* ry)
{
    float2 h0 = unpack_h2(__builtin_bit_cast(unsigned, r01h.x));
    float2 h1 = unpack_h2(__builtin_bit_cast(unsigned, r01h.y));
    float2 h2 = unpack_h2(__builtin_bit_cast(unsigned, r01h.z));
    float2 h3 = unpack_h2(__builtin_bit_cast(unsigned, r01h.w));
    float P0 = fmaf(h0.x, pv.x, fmaf(h0.y, pv.y, fmaf(h1.x, pv.z, h1.y)));
    float P1 = fmaf(h2.x, pv.x, fmaf(h2.y, pv.y, fmaf(h3.x, pv.z, h3.y)));
    float P2 = fmaf(r2.x, pv.x, fmaf(r2.y, pv.y, fmaf(r2.z, pv.z, r2.w)));
    float inv = __builtin_amdgcn_rcpf(P2);
    *rx = fmaf(P0 * inv, FX_, CX_);
    *ry = fmaf(P1 * inv, FY_, CY_);
}

__global__ __launch_bounds__(256) void ba_project_flat_kernel(
    const float4* __restrict__ tMPh,  // [N_MP] (x,y,z,1)
    const KFE*    __restrict__ kfe,   // [N_KF] 32 B packed, L1/L2-hot
    const int*    __restrict__ kf_ids,
    const int*    __restrict__ mp_ids,
    float* __restrict__ out,          // [M,2]
    int M)
{
    size_t t = (size_t)blockIdx.x * 256 + threadIdx.x;
    size_t m0 = t * EPT;

    if (m0 + EPT <= (size_t)M) {
        vint4 k4 = __builtin_nontemporal_load(reinterpret_cast<const vint4*>(kf_ids + m0));
        vint4 m4 = __builtin_nontemporal_load(reinterpret_cast<const vint4*>(mp_ids + m0));
        int kf[EPT] = {k4.x, k4.y, k4.z, k4.w};
        int mp[EPT] = {m4.x, m4.y, m4.z, m4.w};
        // 12 independent 16 B requests in flight before any consumption
        float4 p[EPT], a[EPT], b[EPT];
        #pragma unroll
        for (int i = 0; i < EPT; ++i) p[i] = tMPh[mp[i]];
        #pragma unroll
        for (int i = 0; i < EPT; ++i) {
            const float4* e = reinterpret_cast<const float4*>(kfe + kf[i]);
            a[i] = e[0];   // r01h
            b[i] = e[1];   // r2
        }
        float res[2 * EPT];
        #pragma unroll
        for (int i = 0; i < EPT; ++i)
            project1(a[i], b[i], p[i], &res[2 * i], &res[2 * i + 1]);
        float4* o = reinterpret_cast<float4*>(out + m0 * 2);
        o[0] = make_float4(res[0], res[1], res[2], res[3]);
        o[1] = make_float4(res[4], res[5], res[6], res[7]);
    } else if (m0 < (size_t)M) {
        for (size_t m = m0; m < (size_t)M; ++m) {
            float4 pv = tMPh[mp_ids[m]];
            const float4* e = reinterpret_cast<const float4*>(kfe + kf_ids[m]);
            float rx, ry;
            project1(e[0], e[1], pv, &rx, &ry);
            out[m * 2 + 0] = rx;
            out[m * 2 + 1] = ry;
        }
    }
}

// --- fallback (no ws / oversized N_KF): known-correct direct kernel ---
__global__ __launch_bounds__(256) void ba_project_direct_kernel(
    const float* __restrict__ tMP, const float* __restrict__ tKF,
    const int* __restrict__ kf_ids, const int* __restrict__ mp_ids,
    float* __restrict__ out, int M)
{
    int t = blockIdx.x * blockDim.x + threadIdx.x;
    int m0 = t * 4;
    int mEnd = (m0 + 4 < M) ? (m0 + 4) : M;
    for (int m = m0; m < mEnd; ++m) {
        int kf = kf_ids[m];
        int mp = mp_ids[m];
        const float* K = tKF + (size_t)kf * 16;
        float4 r0 = *reinterpret_cast<const float4*>(K + 0);
        float4 r1 = *reinterpret_cast<const float4*>(K + 4);
        float4 r2 = *reinterpret_cast<const float4*>(K + 8);
        const float* p = tMP + (size_t)mp * 3;
        float x = p[0], y = p[1], z = p[2];
        float P0 = fmaf(r0.x, x, fmaf(r0.y, y, fmaf(r0.z, z, r0.w)));
        float P1 = fmaf(r1.x, x, fmaf(r1.y, y, fmaf(r1.z, z, r1.w)));
        float P2 = fmaf(r2.x, x, fmaf(r2.y, y, fmaf(r2.z, z, r2.w)));
        float inv = 1.0f / P2;
        out[2 * (size_t)m + 0] = fmaf(P0 * inv, FX_, CX_);
        out[2 * (size_t)m + 1] = fmaf(P1 * inv, FY_, CY_);
    }
}

extern "C" void kernel_launch(void* const* d_in, const int* in_sizes, int n_in,
                              void* d_out, int out_size, void* d_ws, size_t ws_size,
                              hipStream_t stream) {
    const float* tMP    = (const float*)d_in[0]; // [N_MP,3]
    const float* tKF    = (const float*)d_in[1]; // [N_KF,4,4]
    const int*   kf_ids = (const int*)d_in[2];   // [M]
    const int*   mp_ids = (const int*)d_in[3];   // [M]
    float* out = (float*)d_out;                  // [M,2]
    int M    = in_sizes[2];
    int N_MP = in_sizes[0] / 3;
    int N_KF = in_sizes[1] / 16;

    const size_t KFE_BYTES = (size_t)MAX_KF * sizeof(KFE);   // 64 KB
    size_t need_ws = KFE_BYTES + (size_t)N_MP * sizeof(float4);

    if (N_KF <= MAX_KF && ws_size >= need_ws) {
        KFE*    kfe  = (KFE*)d_ws;
        float4* tMPh = (float4*)((char*)d_ws + KFE_BYTES);
        int np = (N_MP > N_KF ? N_MP : N_KF);
        pack_kernel<<<(np + 255) / 256, 256, 0, stream>>>(
            tMP, tKF, tMPh, kfe, N_MP, N_KF);
        int perBlock = 256 * EPT;
        int nb = (M + perBlock - 1) / perBlock;
        ba_project_flat_kernel<<<nb, 256, 0, stream>>>(
            tMPh, kfe, kf_ids, mp_ids, out, M);
    } else {
        int threads = (M + 3) / 4;
        int grid = (threads + 255) / 256;
        ba_project_direct_kernel<<<grid, 256, 0, stream>>>(
            tMP, tKF, kf_ids, mp_ids, out, M);
    }
}